// Round 1
// baseline (58.598 us; speedup 1.0000x reference)
//
#include <hip/hip_runtime.h>
#include <hip/hip_bf16.h>
#include <stdint.h>

typedef __attribute__((ext_vector_type(8))) __bf16 bf16x8;
typedef __attribute__((ext_vector_type(4))) float f32x4;

static constexpr int Bb = 32, Ss = 512, Dd = 1024, Rr = 256;
static constexpr int M1 = Bb * Ss;  // 16384

__device__ __forceinline__ void gload_lds16(const void* g, void* l) {
  __builtin_amdgcn_global_load_lds(
      (const __attribute__((address_space(1))) void*)g,
      (__attribute__((address_space(3))) void*)l, 16, 0, 0);
}

// ---------------- prep: Lt[r][d] = L[d][r] (bf16), Rb = R (bf16) -------------
__global__ __launch_bounds__(256) void prep_kernel(
    const float* __restrict__ L, const float* __restrict__ R,
    __bf16* __restrict__ Lt, __bf16* __restrict__ Rb) {
  int i = blockIdx.x * 256 + threadIdx.x;
  if (i < Rr * Dd) {
    int r = i >> 10;           // 0..255
    int d = i & (Dd - 1);      // 0..1023
    Lt[i] = (__bf16)L[d * Rr + r];
    Rb[i] = (__bf16)R[i];
  }
}

// ---------------- stage 1: left = batch@L, rightT = batch@R^T ----------------
// C[M1=16384, N=256] (bf16) = A_f32[M1, K=1024] x Bt[N, K] (bf16, B^T layout)
// 128x128 tile, BK=32, 4 waves, 16x16x32 bf16 MFMA. A reg-staged w/ convert,
// B via global_load_lds(16B).
__global__ __launch_bounds__(256, 2) void proj_gemm(
    const float* __restrict__ batch,
    const __bf16* __restrict__ BtL,   // [256][1024]
    const __bf16* __restrict__ BtR,   // [256][1024]
    __bf16* __restrict__ outL,        // [16384][256]
    __bf16* __restrict__ outR) {
  const int nt = blockIdx.x;     // 0..1
  const int mt = blockIdx.y;     // 0..127
  const int which = blockIdx.z;  // 0=L, 1=R
  const __bf16* Bt = which ? BtR : BtL;
  __bf16* out = which ? outR : outL;
  const int m0 = mt * 128, n0 = nt * 128;

  __shared__ __align__(16) char smem[16384];
  char* At = smem;            // [128][32] bf16 linear
  char* Btile = smem + 8192;  // [128][32] bf16 linear

  const int t = threadIdx.x;
  const int lane = t & 63;
  const int wave = t >> 6;
  const int wr = wave >> 1, wc = wave & 1;

  f32x4 acc[4][4] = {};

  for (int k0 = 0; k0 < Dd; k0 += 32) {
    __syncthreads();  // previous iteration's LDS reads done
    // ---- stage A: fp32 -> bf16 reg-convert, 8 elems/thread, 2 passes ----
#pragma unroll
    for (int p = 0; p < 2; ++p) {
      int e = p * 256 + t;
      int row = e >> 2;           // 0..127
      int kk = (e & 3) * 8;       // 0,8,16,24
      const float* src = batch + (size_t)(m0 + row) * Dd + k0 + kk;
      f32x4 f0 = *(const f32x4*)src;
      f32x4 f1 = *(const f32x4*)(src + 4);
      bf16x8 v;
      v[0] = (__bf16)f0[0]; v[1] = (__bf16)f0[1];
      v[2] = (__bf16)f0[2]; v[3] = (__bf16)f0[3];
      v[4] = (__bf16)f1[0]; v[5] = (__bf16)f1[1];
      v[6] = (__bf16)f1[2]; v[7] = (__bf16)f1[3];
      *(bf16x8*)(At + e * 16) = v;
    }
    // ---- stage B: global_load_lds 16B, 2 calls ----
#pragma unroll
    for (int p = 0; p < 2; ++p) {
      int e = p * 256 + t;
      int row = e >> 2;
      int kp = e & 3;
      gload_lds16(Bt + (size_t)(n0 + row) * Dd + k0 + kp * 8, Btile + e * 16);
    }
    __syncthreads();  // compiler drains vmcnt/lgkmcnt before s_barrier

    bf16x8 a[4], b[4];
#pragma unroll
    for (int m = 0; m < 4; ++m)
      a[m] = *(const bf16x8*)(At + (wr * 64 + m * 16 + (lane & 15)) * 64 +
                              (lane >> 4) * 16);
#pragma unroll
    for (int n = 0; n < 4; ++n)
      b[n] = *(const bf16x8*)(Btile + (wc * 64 + n * 16 + (lane & 15)) * 64 +
                              (lane >> 4) * 16);
#pragma unroll
    for (int m = 0; m < 4; ++m)
#pragma unroll
      for (int n = 0; n < 4; ++n)
        acc[m][n] =
            __builtin_amdgcn_mfma_f32_16x16x32_bf16(a[m], b[n], acc[m][n], 0, 0, 0);
  }

  // ---- epilogue: bf16 store to ws (C/D: col=lane&15, row=(lane>>4)*4+i) ----
  const int col = lane & 15, rgrp = lane >> 4;
#pragma unroll
  for (int m = 0; m < 4; ++m) {
    int r0 = m0 + wr * 64 + m * 16 + rgrp * 4;
#pragma unroll
    for (int n = 0; n < 4; ++n) {
      int c = n0 + wc * 64 + n * 16 + col;
#pragma unroll
      for (int i = 0; i < 4; ++i)
        out[(size_t)(r0 + i) * Rr + c] = (__bf16)acc[m][n][i];
    }
  }
}

// ---------------- stage 2: logits[b] = left[b] @ rightT[b]^T + bias ----------
// Per batch: C[512,512] f32 = A[512,256] x Bt[512,256] (both bf16, K-contig)
__global__ __launch_bounds__(256, 2) void score_gemm(
    const __bf16* __restrict__ left,   // [B*512][256]
    const __bf16* __restrict__ right,  // [B*512][256]
    const float* __restrict__ biasp,
    float* __restrict__ out) {         // [B][512][512]
  const int nt = blockIdx.x;  // 0..3
  const int mt = blockIdx.y;  // 0..3
  const int bz = blockIdx.z;  // 0..31
  const __bf16* A = left + (size_t)bz * Ss * Rr;
  const __bf16* Bt = right + (size_t)bz * Ss * Rr;
  float* O = out + (size_t)bz * Ss * Ss;
  const int m0 = mt * 128, n0 = nt * 128;

  __shared__ __align__(16) char smem[16384];
  char* At = smem;
  char* Btile = smem + 8192;

  const int t = threadIdx.x;
  const int lane = t & 63;
  const int wave = t >> 6;
  const int wr = wave >> 1, wc = wave & 1;

  f32x4 acc[4][4] = {};

  for (int k0 = 0; k0 < Rr; k0 += 32) {
    __syncthreads();
#pragma unroll
    for (int p = 0; p < 2; ++p) {
      int e = p * 256 + t;
      int row = e >> 2;
      int kp = e & 3;
      gload_lds16(A + (size_t)(m0 + row) * Rr + k0 + kp * 8, At + e * 16);
      gload_lds16(Bt + (size_t)(n0 + row) * Rr + k0 + kp * 8, Btile + e * 16);
    }
    __syncthreads();

    bf16x8 a[4], b[4];
#pragma unroll
    for (int m = 0; m < 4; ++m)
      a[m] = *(const bf16x8*)(At + (wr * 64 + m * 16 + (lane & 15)) * 64 +
                              (lane >> 4) * 16);
#pragma unroll
    for (int n = 0; n < 4; ++n)
      b[n] = *(const bf16x8*)(Btile + (wc * 64 + n * 16 + (lane & 15)) * 64 +
                              (lane >> 4) * 16);
#pragma unroll
    for (int m = 0; m < 4; ++m)
#pragma unroll
      for (int n = 0; n < 4; ++n)
        acc[m][n] =
            __builtin_amdgcn_mfma_f32_16x16x32_bf16(a[m], b[n], acc[m][n], 0, 0, 0);
  }

  const float bias = *biasp;
  const int col = lane & 15, rgrp = lane >> 4;
#pragma unroll
  for (int m = 0; m < 4; ++m) {
    int r0 = m0 + wr * 64 + m * 16 + rgrp * 4;
#pragma unroll
    for (int n = 0; n < 4; ++n) {
      int c = n0 + wc * 64 + n * 16 + col;
#pragma unroll
      for (int i = 0; i < 4; ++i)
        O[(size_t)(r0 + i) * Ss + c] = acc[m][n][i] + bias;
    }
  }
}

extern "C" void kernel_launch(void* const* d_in, const int* in_sizes, int n_in,
                              void* d_out, int out_size, void* d_ws,
                              size_t ws_size, hipStream_t stream) {
  const float* batch = (const float*)d_in[0];  // [32][512][1024]
  const float* projL = (const float*)d_in[1];  // [1024][256]
  const float* projR = (const float*)d_in[2];  // [256][1024]
  const float* bias = (const float*)d_in[3];   // [1]
  float* out = (float*)d_out;                  // [32][512][512]

  char* ws = (char*)d_ws;
  // ws layout (17,825,792 bytes total):
  __bf16* left = (__bf16*)(ws);                        // 8,388,608 B
  __bf16* right = (__bf16*)(ws + 8388608);             // 8,388,608 B
  __bf16* Lt = (__bf16*)(ws + 16777216);               //   524,288 B
  __bf16* Rb = (__bf16*)(ws + 16777216 + 524288);      //   524,288 B

  prep_kernel<<<dim3(1024), dim3(256), 0, stream>>>(projL, projR, Lt, Rb);
  proj_gemm<<<dim3(2, 128, 2), dim3(256), 0, stream>>>(batch, Lt, Rb, left,
                                                       right);
  score_gemm<<<dim3(4, 4, 32), dim3(256), 0, stream>>>(left, right, bias, out);
}